// Round 6
// baseline (286.858 us; speedup 1.0000x reference)
//
#include <hip/hip_runtime.h>
#include <hip/hip_fp16.h>
#include <math.h>

#define IN_CH 8
#define HID   64
#define EMB   32
#define SCAN_T 4096     // 16 blocks x 256 for the histogram scan
#define HBLK  256       // blocks in hist/scatter phases
#define BW    128       // nodes per bucket (dst >> 7)
#define NBMAX 800       // max buckets supported (N <= 102400)

static __device__ __forceinline__ __half2 u2h2(unsigned u) {
    union { unsigned u; __half2 h; } c; c.u = u; return c.h;
}
static __device__ __forceinline__ unsigned h22u(__half2 h) {
    union { unsigned u; __half2 h; } c; c.h = h; return c.u;
}

// ------------------------------------------------- pass A1: per-block bucket histogram
__global__ __launch_bounds__(256) void hist_kernel(const int* __restrict__ ei,
                                                   int* __restrict__ hist2, int E, int NB) {
    __shared__ int lh[NBMAX];
    int b = blockIdx.x, t = threadIdx.x;
    for (int i = t; i < NB; i += 256) lh[i] = 0;
    __syncthreads();
    int per = (E + gridDim.x - 1) / gridDim.x;
    int e0 = b * per, e1 = min(e0 + per, E);
    for (int e = e0 + t; e < e1; e += 256)
        atomicAdd(&lh[ei[E + e] >> 7], 1);
    __syncthreads();
    for (int i = t; i < NB; i += 256) hist2[b * NB + i] = lh[i];
}

// ------------------------------------------------- hist scan (bucket-major logical order)
__global__ void hscanA_kernel(const int* __restrict__ hist2, int* __restrict__ tsum,
                              int M, int NB) {
    int tid = blockIdx.x * blockDim.x + threadIdx.x;
    int chunk = (M + SCAN_T - 1) / SCAN_T;
    int start = tid * chunk, end = min(start + chunk, M);
    int s = 0;
    for (int l = start; l < end; l++) s += hist2[(l & (HBLK - 1)) * NB + (l >> 8)];
    tsum[tid] = s;
}

__global__ __launch_bounds__(256) void hscanB_kernel(const int* __restrict__ tsum,
                                                     int* __restrict__ tpre) {
    __shared__ int bsum[256];
    int t = threadIdx.x;
    int s = 0;
    #pragma unroll
    for (int i = 0; i < 16; i++) s += tsum[t * 16 + i];
    bsum[t] = s;
    __syncthreads();
    for (int off = 1; off < 256; off <<= 1) {
        int v = (t >= off) ? bsum[t - off] : 0;
        __syncthreads();
        bsum[t] += v;
        __syncthreads();
    }
    int run = (t == 0) ? 0 : bsum[t - 1];
    #pragma unroll
    for (int i = 0; i < 16; i++) { tpre[t * 16 + i] = run; run += tsum[t * 16 + i]; }
}

__global__ void hscanC_kernel(const int* __restrict__ hist2, const int* __restrict__ tpre,
                              int* __restrict__ off2, int M, int NB) {
    int tid = blockIdx.x * blockDim.x + threadIdx.x;
    int chunk = (M + SCAN_T - 1) / SCAN_T;
    int start = tid * chunk, end = min(start + chunk, M);
    int run = tpre[tid];
    for (int l = start; l < end; l++) {
        int ph = (l & (HBLK - 1)) * NB + (l >> 8);
        off2[ph] = run;
        run += hist2[ph];
    }
}

// ------------------------------------------------- pass A2: scatter edges (packed src|li)
__global__ __launch_bounds__(256) void scat_kernel(const int* __restrict__ ei,
                                                   const int* __restrict__ off2,
                                                   int* __restrict__ staged, int E, int NB) {
    __shared__ int lcur[NBMAX];
    int b = blockIdx.x, t = threadIdx.x;
    for (int i = t; i < NB; i += 256) lcur[i] = off2[b * NB + i];
    __syncthreads();
    int per = (E + gridDim.x - 1) / gridDim.x;
    int e0 = b * per, e1 = min(e0 + per, E);
    for (int e = e0 + t; e < e1; e += 256) {
        int src = ei[e], dst = ei[E + e];
        int pos = atomicAdd(&lcur[dst >> 7], 1);
        staged[pos] = src | ((dst & (BW - 1)) << 17);   // src<2^17, li<128
    }
}

// ------------------------------------------------- pass B: per-bucket CSR build
__global__ __launch_bounds__(256) void bucket_kernel(const int* __restrict__ staged,
                                                     const int* __restrict__ off2,
                                                     int* __restrict__ row_off,
                                                     int* __restrict__ csr,
                                                     int N, int E, int NB) {
    __shared__ int cnt[BW], offx[BW], cur[BW];
    int b = blockIdx.x, t = threadIdx.x;
    int base = b * BW;
    int s0 = off2[b];
    int s1 = (b + 1 < NB) ? off2[b + 1] : E;
    if (t < BW) cnt[t] = 0;
    __syncthreads();
    for (int e = s0 + t; e < s1; e += 256)
        atomicAdd(&cnt[staged[e] >> 17], 1);
    __syncthreads();
    if (t < BW) offx[t] = cnt[t];
    __syncthreads();
    for (int off = 1; off < BW; off <<= 1) {
        int v = (t >= off && t < BW) ? offx[t - off] : 0;
        __syncthreads();
        if (t < BW) offx[t] += v;
        __syncthreads();
    }
    if (t < BW) {
        int ex = offx[t] - cnt[t];
        if (base + t < N) row_off[base + t] = s0 + ex;
        cnt[t] = ex;
        cur[t] = 0;
    }
    if (b == NB - 1 && t == 0) row_off[N] = s1;
    __syncthreads();
    for (int e = s0 + t; e < s1; e += 256) {
        int v = staged[e];
        int li = v >> 17;
        int pos = s0 + cnt[li] + atomicAdd(&cur[li], 1);
        csr[pos] = v & 0x1FFFF;
    }
}

// ------------------------------------------------- gather1: mean of x over neighbors
__global__ __launch_bounds__(256) void gather1_kernel(
        const float* __restrict__ x, const int* __restrict__ row_off,
        const int* __restrict__ csr, float* __restrict__ aggr, int N) {
    int t = threadIdx.x;
    int lane = t & 63;
    int node = blockIdx.x * 4 + (t >> 6);
    if (node >= N) return;
    int r0 = row_off[node], r1 = row_off[node + 1];
    int deg = r1 - r0;

    int my = (r0 + lane < r1) ? csr[r0 + lane] : 0;
    int g = lane >> 2;        // 16 groups
    int q = lane & 3;         // float2 slot -> channels 2q, 2q+1
    float ax = 0.0f, ay = 0.0f;
    int lim = min(deg, 64);
    int i = g;
    for (; i + 16 < lim; i += 32) {           // unroll 2
        int s0 = __shfl(my, i), s1 = __shfl(my, i + 16);
        float2 v0 = *(const float2*)(x + (size_t)s0 * IN_CH + q * 2);
        float2 v1 = *(const float2*)(x + (size_t)s1 * IN_CH + q * 2);
        ax += v0.x + v1.x; ay += v0.y + v1.y;
    }
    if (i < lim) {
        int s0 = __shfl(my, i);
        float2 v0 = *(const float2*)(x + (size_t)s0 * IN_CH + q * 2);
        ax += v0.x; ay += v0.y;
    }
    for (int e = r0 + 64 + g; e < r1; e += 16) {   // rare deg>64 tail
        int s0 = csr[e];
        float2 v0 = *(const float2*)(x + (size_t)s0 * IN_CH + q * 2);
        ax += v0.x; ay += v0.y;
    }
    ax += __shfl_xor(ax, 4);  ay += __shfl_xor(ay, 4);
    ax += __shfl_xor(ax, 8);  ay += __shfl_xor(ay, 8);
    ax += __shfl_xor(ax, 16); ay += __shfl_xor(ay, 16);
    ax += __shfl_xor(ax, 32); ay += __shfl_xor(ay, 32);

    float inv = 1.0f / fmaxf((float)deg, 1.0f);
    if (lane < 4)
        ((float2*)(aggr + (size_t)node * IN_CH))[q] = make_float2(ax * inv, ay * inv);
}

// ------------------------------------------------- dense1b: node-per-thread dense chain
// h = relu(aggr@W1l + b1 + x@W1r); pA/pB = h@W2l (fp16 halves); self = h@W2r + b2.
__global__ __launch_bounds__(128) void dense1b_kernel(
        const float* __restrict__ x, const float* __restrict__ aggr,
        const float* __restrict__ W1l, const float* __restrict__ b1,
        const float* __restrict__ W1r,
        const float* __restrict__ W2l, const float* __restrict__ b2,
        const float* __restrict__ W2r,
        unsigned* __restrict__ pA, unsigned* __restrict__ pB,
        float* __restrict__ selfb, int N) {
    int n = blockIdx.x * 128 + threadIdx.x;
    if (n >= N) return;

    float av[IN_CH], xv[IN_CH];
    {
        float4 a0 = ((const float4*)(aggr + (size_t)n * IN_CH))[0];
        float4 a1 = ((const float4*)(aggr + (size_t)n * IN_CH))[1];
        av[0] = a0.x; av[1] = a0.y; av[2] = a0.z; av[3] = a0.w;
        av[4] = a1.x; av[5] = a1.y; av[6] = a1.z; av[7] = a1.w;
        float4 b0 = ((const float4*)(x + (size_t)n * IN_CH))[0];
        float4 b1v = ((const float4*)(x + (size_t)n * IN_CH))[1];
        xv[0] = b0.x; xv[1] = b0.y; xv[2] = b0.z; xv[3] = b0.w;
        xv[4] = b1v.x; xv[5] = b1v.y; xv[6] = b1v.z; xv[7] = b1v.w;
    }

    float pacc[EMB], sacc[EMB];
    #pragma unroll
    for (int j = 0; j < EMB; j++) { pacc[j] = 0.0f; sacc[j] = b2[j]; }

    for (int k = 0; k < HID; k++) {
        float hk = b1[k];
        #pragma unroll
        for (int c = 0; c < IN_CH; c++)
            hk += av[c] * W1l[c * HID + k] + xv[c] * W1r[c * HID + k];
        hk = fmaxf(hk, 0.0f);
        const float* wl = W2l + k * EMB;
        const float* wr = W2r + k * EMB;
        #pragma unroll
        for (int j = 0; j < EMB; j++) {
            pacc[j] += hk * wl[j];
            sacc[j] += hk * wr[j];
        }
    }

    unsigned up[16];
    #pragma unroll
    for (int m = 0; m < 16; m++)
        up[m] = h22u(__floats2half2_rn(pacc[2 * m], pacc[2 * m + 1]));
    uint4* ppa = (uint4*)(pA + (size_t)n * 8);
    ppa[0] = make_uint4(up[0], up[1], up[2], up[3]);
    ppa[1] = make_uint4(up[4], up[5], up[6], up[7]);
    uint4* ppb = (uint4*)(pB + (size_t)n * 8);
    ppb[0] = make_uint4(up[8], up[9], up[10], up[11]);
    ppb[1] = make_uint4(up[12], up[13], up[14], up[15]);
    float4* sp = (float4*)(selfb + (size_t)n * EMB);
    #pragma unroll
    for (int m = 0; m < 8; m++)
        sp[m] = make_float4(sacc[4 * m], sacc[4 * m + 1], sacc[4 * m + 2], sacc[4 * m + 3]);
}

// ------------------------------------------------- gather2: one channel-half pass
// phase 0: gather pA (ch 0..15), z-low -> zA (fp16x2).
// phase 1: gather pB (ch 16..31), load zA, head MLP, sigmoid -> out.
// Hot array (3.2 MB) is L2-resident; csr/selfb/zA loads are non-temporal.
__global__ __launch_bounds__(256) void gather2_kernel(
        const unsigned* __restrict__ pX, const float* __restrict__ selfb,
        const int* __restrict__ row_off, const int* __restrict__ csr,
        unsigned* __restrict__ zA,
        const float* __restrict__ Wh1, const float* __restrict__ bh1,
        const float* __restrict__ Wh2, const float* __restrict__ bh2,
        float* __restrict__ out, int N, int phase) {
    __shared__ float sH1[EMB * 16];
    __shared__ float sbh1[16];
    __shared__ float sH2[16];
    int t = threadIdx.x;
    if (phase) {
        for (int i = t; i < EMB * 16; i += 256) sH1[i] = Wh1[i];
        if (t < 16) { sbh1[t] = bh1[t]; sH2[t] = Wh2[t]; }
        __syncthreads();
    }

    int lane = t & 63;
    int node = blockIdx.x * 4 + (t >> 6);
    if (node >= N) return;
    int r0 = row_off[node], r1 = row_off[node + 1];
    int deg = r1 - r0;

    int my = (r0 + lane < r1) ? __builtin_nontemporal_load(csr + r0 + lane) : 0;
    int g = lane >> 3;          // 8 groups
    int c4 = lane & 7;          // uint index within 32B row (channel pair)
    __half2 hacc = __floats2half2_rn(0.0f, 0.0f);
    int lim = min(deg, 64);
    int i = g;
    for (; i + 8 < lim; i += 16) {               // unroll 2
        int s0 = __shfl(my, i), s1 = __shfl(my, i + 8);
        hacc = __hadd2(hacc, u2h2(pX[(size_t)s0 * 8 + c4]));
        hacc = __hadd2(hacc, u2h2(pX[(size_t)s1 * 8 + c4]));
    }
    if (i < lim)
        hacc = __hadd2(hacc, u2h2(pX[(size_t)__shfl(my, i) * 8 + c4]));
    for (int e = r0 + 64 + g; e < r1; e += 8)    // rare deg>64 tail
        hacc = __hadd2(hacc, u2h2(pX[(size_t)__builtin_nontemporal_load(csr + e) * 8 + c4]));

    hacc = __hadd2(hacc, u2h2(__shfl_xor(h22u(hacc), 8)));
    hacc = __hadd2(hacc, u2h2(__shfl_xor(h22u(hacc), 16)));
    hacc = __hadd2(hacc, u2h2(__shfl_xor(h22u(hacc), 32)));
    float2 f = __half22float2(hacc);             // sums for channels (16*phase + 2*c4, +1)

    float inv = 1.0f / fmaxf((float)deg, 1.0f);
    const float* sb = selfb + (size_t)node * EMB + phase * 16 + c4 * 2;
    float zx = fmaxf(f.x * inv + __builtin_nontemporal_load(sb), 0.0f);
    float zy = fmaxf(f.y * inv + __builtin_nontemporal_load(sb + 1), 0.0f);

    if (!phase) {
        if (g == 0)
            zA[(size_t)node * 8 + c4] = h22u(__floats2half2_rn(zx, zy));
        return;
    }

    // phase 1: zx,zy = high pair (16+2c4, 17+2c4); load low half
    float2 zlo = __half22float2(u2h2(__builtin_nontemporal_load(zA + (size_t)node * 8 + c4)));

    int j = lane & 31;
    int pi = (j >> 1) & 7;
    float lox = __shfl(zlo.x, pi), loy = __shfl(zlo.y, pi);
    float hix = __shfl(zx, pi),    hiy = __shfl(zy, pi);
    float z = (j < 16) ? ((j & 1) ? loy : lox) : ((j & 1) ? hiy : hix);

    int i2 = lane & 15;
    float hid = sbh1[i2];
    #pragma unroll
    for (int k = 0; k < EMB; k++) {
        float zk = __shfl(z, k);
        hid += zk * sH1[k * 16 + i2];
    }
    float part = fmaxf(hid, 0.0f) * sH2[i2];
    part += __shfl_xor(part, 1);
    part += __shfl_xor(part, 2);
    part += __shfl_xor(part, 4);
    part += __shfl_xor(part, 8);

    if (lane == 0) {
        float logit = part + bh2[0];
        out[node] = 1.0f / (1.0f + expf(-logit));
    }
}

// ---------------------------------------------------------------- launch
extern "C" void kernel_launch(void* const* d_in, const int* in_sizes, int n_in,
                              void* d_out, int out_size, void* d_ws, size_t ws_size,
                              hipStream_t stream) {
    const float* x   = (const float*)d_in[0];
    const int*   ei  = (const int*)d_in[1];
    const float* W1l = (const float*)d_in[2];
    const float* b1  = (const float*)d_in[3];
    const float* W1r = (const float*)d_in[4];
    const float* W2l = (const float*)d_in[5];
    const float* b2  = (const float*)d_in[6];
    const float* W2r = (const float*)d_in[7];
    const float* Wh1 = (const float*)d_in[8];
    const float* bh1 = (const float*)d_in[9];
    const float* Wh2 = (const float*)d_in[10];
    const float* bh2 = (const float*)d_in[11];

    int N = in_sizes[0] / IN_CH;     // 100000
    int E = in_sizes[1] / 2;         // 3200000
    int NB = (N + BW - 1) / BW;      // 782 buckets
    int M  = NB * HBLK;

    // workspace layout:
    // [staged int E][hist2 M][off2 M][tsum 4096][tpre 4096][row_off N+1][csr E]
    // [aggr 8N f32][selfb 32N f32][pA 8N u32][pB 8N u32][zA 8N u32]
    int* staged   = (int*)d_ws;
    int* hist2    = staged + E;
    int* off2     = hist2 + M;
    int* tsum     = off2 + M;
    int* tpre     = tsum + SCAN_T;
    int* row_off  = tpre + SCAN_T;
    int* csr      = row_off + (N + 1);
    float* aggr   = (float*)(csr + E);
    float* selfb  = aggr + (size_t)N * IN_CH;
    unsigned* pA  = (unsigned*)(selfb + (size_t)N * EMB);
    unsigned* pB  = pA + (size_t)N * 8;
    unsigned* zA  = pB + (size_t)N * 8;

    hist_kernel   <<<HBLK, 256, 0, stream>>>(ei, hist2, E, NB);
    hscanA_kernel <<<SCAN_T / 256, 256, 0, stream>>>(hist2, tsum, M, NB);
    hscanB_kernel <<<1, 256, 0, stream>>>(tsum, tpre);
    hscanC_kernel <<<SCAN_T / 256, 256, 0, stream>>>(hist2, tpre, off2, M, NB);
    scat_kernel   <<<HBLK, 256, 0, stream>>>(ei, off2, staged, E, NB);
    bucket_kernel <<<NB, 256, 0, stream>>>(staged, off2, row_off, csr, N, E, NB);
    gather1_kernel<<<(N + 3) / 4, 256, 0, stream>>>(x, row_off, csr, aggr, N);
    dense1b_kernel<<<(N + 127) / 128, 128, 0, stream>>>(x, aggr, W1l, b1, W1r,
                                                        W2l, b2, W2r, pA, pB, selfb, N);
    gather2_kernel<<<(N + 3) / 4, 256, 0, stream>>>(pA, selfb, row_off, csr, zA,
                                                    Wh1, bh1, Wh2, bh2, (float*)d_out, N, 0);
    gather2_kernel<<<(N + 3) / 4, 256, 0, stream>>>(pB, selfb, row_off, csr, zA,
                                                    Wh1, bh1, Wh2, bh2, (float*)d_out, N, 1);
}